// Round 1
// baseline (928.865 us; speedup 1.0000x reference)
//
#include <hip/hip_runtime.h>
#include <stdint.h>

typedef unsigned short u16;
typedef __attribute__((ext_vector_type(4))) float f32x4;
typedef __attribute__((ext_vector_type(8))) short s16x8;

#define TB 4
#define TT 4096
#define TD 1024

__device__ __forceinline__ u16 f2bf(float f) {
  union { float f; uint32_t u; } v; v.f = f;
  return (u16)((v.u + 0x7FFFu + ((v.u >> 16) & 1u)) >> 16);
}

#define GLOAD_LDS16(g, l) __builtin_amdgcn_global_load_lds( \
    (const __attribute__((address_space(1))) void*)(g),      \
    (__attribute__((address_space(3))) void*)(l), 16, 0, 0)

// ---------------- cast fp32 -> bf16, vectorized ----------------
__global__ void cast_bf16(const float* __restrict__ in, u16* __restrict__ out, int n4) {
  int i = blockIdx.x * blockDim.x + threadIdx.x;
  int stride = gridDim.x * blockDim.x;
  for (; i < n4; i += stride) {
    float4 v = ((const float4*)in)[i];
    ushort4 o;
    o.x = f2bf(v.x); o.y = f2bf(v.y); o.z = f2bf(v.z); o.w = f2bf(v.w);
    ((ushort4*)out)[i] = o;
  }
}

// ---------------- GEMM: C[M,N] = A[M,K] * Bt[N,K]^T (both bf16, K contiguous) ----------------
// 128x128 tile, 256 threads (4 waves in 2x2), BK=32, mfma_f32_16x16x32_bf16
template<bool OUT_BF16>
__global__ __launch_bounds__(256)
void gemm_bt(const u16* __restrict__ A, const u16* __restrict__ Bt,
             void* __restrict__ C, int M, int N, int K, float scale) {
  __shared__ u16 lsA[128 * 32];
  __shared__ u16 lsB[128 * 32];
  const int tid  = threadIdx.x;
  const int lane = tid & 63;
  const int wid  = tid >> 6;
  const int wm   = wid >> 1;   // 0..1
  const int wn   = wid & 1;    // 0..1
  const int brow = blockIdx.y * 128;
  const int bcol = blockIdx.x * 128;

  f32x4 acc[4][4];
#pragma unroll
  for (int m = 0; m < 4; ++m)
#pragma unroll
    for (int n = 0; n < 4; ++n) acc[m][n] = (f32x4){0.f, 0.f, 0.f, 0.f};

  const int nk = K >> 5;  // BK = 32
  for (int kt = 0; kt < nk; ++kt) {
    // stage 128x32 bf16 tiles for A and B: 512 16B-chunks each, 2 per thread
#pragma unroll
    for (int i = 0; i < 2; ++i) {
      int c    = i * 256 + tid;   // chunk id 0..511
      int row  = c >> 2;          // 0..127
      int col8 = c & 3;           // which 8-elem group in the 32-wide row
      const u16* ga = A  + (size_t)(brow + row) * K + kt * 32 + col8 * 8;
      const u16* gb = Bt + (size_t)(bcol + row) * K + kt * 32 + col8 * 8;
      // LDS dest is wave-uniform base; HW adds lane*16B
      u16* la = &lsA[(size_t)(i * 256 + wid * 64) * 8];
      u16* lb = &lsB[(size_t)(i * 256 + wid * 64) * 8];
      GLOAD_LDS16(ga, la);
      GLOAD_LDS16(gb, lb);
    }
    __syncthreads();

    const int r16 = lane & 15;
    const int k8  = lane >> 4;  // 0..3 -> k = k8*8 .. +8
    s16x8 af[4], bf[4];
#pragma unroll
    for (int m = 0; m < 4; ++m)
      af[m] = *(const s16x8*)&lsA[(size_t)(wm * 64 + m * 16 + r16) * 32 + k8 * 8];
#pragma unroll
    for (int n = 0; n < 4; ++n)
      bf[n] = *(const s16x8*)&lsB[(size_t)(wn * 64 + n * 16 + r16) * 32 + k8 * 8];
#pragma unroll
    for (int m = 0; m < 4; ++m)
#pragma unroll
      for (int n = 0; n < 4; ++n)
        acc[m][n] = __builtin_amdgcn_mfma_f32_16x16x32_bf16(af[m], bf[n], acc[m][n], 0, 0, 0);
    __syncthreads();
  }

  // epilogue: C/D layout col = lane&15, row = (lane>>4)*4 + reg
  const int c16 = lane & 15;
  const int rhi = lane >> 4;
#pragma unroll
  for (int m = 0; m < 4; ++m)
#pragma unroll
    for (int n = 0; n < 4; ++n)
#pragma unroll
      for (int r = 0; r < 4; ++r) {
        int grow = brow + wm * 64 + m * 16 + rhi * 4 + r;
        int gcol = bcol + wn * 64 + n * 16 + c16;
        float v = acc[m][n][r] * scale;
        if (OUT_BF16) ((u16*)C)[(size_t)grow * N + gcol] = f2bf(v);
        else          ((float*)C)[(size_t)grow * N + gcol] = v;
      }
}

// ---------------- transpose bf16: V[B][T][D] -> Vt[B][D][T] ----------------
__global__ __launch_bounds__(256)
void transpose_bf16(const u16* __restrict__ V, u16* __restrict__ Vt) {
  __shared__ u16 tile[32][33];
  int b  = blockIdx.z;
  int t0 = blockIdx.y * 32;
  int e0 = blockIdx.x * 32;
  int tr = threadIdx.x >> 5;  // 0..7
  int tc = threadIdx.x & 31;
  const u16* Vb  = V  + (size_t)b * TT * TD;
  u16*       Vtb = Vt + (size_t)b * TT * TD;
#pragma unroll
  for (int i = 0; i < 4; ++i) {
    int r = tr + i * 8;
    tile[r][tc] = Vb[(size_t)(t0 + r) * TD + e0 + tc];
  }
  __syncthreads();
#pragma unroll
  for (int i = 0; i < 4; ++i) {
    int r = tr + i * 8;
    Vtb[(size_t)(e0 + r) * TT + t0 + tc] = tile[tc][r];
  }
}

// ---------------- row softmax: S[4096] fp32 -> P[4096] bf16 (1/l folded in) ----------------
__global__ __launch_bounds__(256)
void softmax_rows(const float* __restrict__ S, u16* __restrict__ P) {
  __shared__ float red_m[4];
  __shared__ float red_s[4];
  int row  = blockIdx.x;
  int tid  = threadIdx.x;
  int lane = tid & 63;
  int wid  = tid >> 6;
  const float4* Sr = (const float4*)(S + (size_t)row * 4096);

  float4 v[4];
  float m = -1e30f;
#pragma unroll
  for (int i = 0; i < 4; ++i) {
    v[i] = Sr[tid + i * 256];
    m = fmaxf(m, fmaxf(fmaxf(v[i].x, v[i].y), fmaxf(v[i].z, v[i].w)));
  }
#pragma unroll
  for (int off = 32; off >= 1; off >>= 1) m = fmaxf(m, __shfl_xor(m, off));
  if (lane == 0) red_m[wid] = m;
  __syncthreads();
  m = fmaxf(fmaxf(red_m[0], red_m[1]), fmaxf(red_m[2], red_m[3]));

  float e[16];
  float s = 0.f;
#pragma unroll
  for (int i = 0; i < 4; ++i) {
    e[i * 4 + 0] = __expf(v[i].x - m);
    e[i * 4 + 1] = __expf(v[i].y - m);
    e[i * 4 + 2] = __expf(v[i].z - m);
    e[i * 4 + 3] = __expf(v[i].w - m);
    s += e[i * 4 + 0] + e[i * 4 + 1] + e[i * 4 + 2] + e[i * 4 + 3];
  }
#pragma unroll
  for (int off = 32; off >= 1; off >>= 1) s += __shfl_xor(s, off);
  if (lane == 0) red_s[wid] = s;
  __syncthreads();
  s = red_s[0] + red_s[1] + red_s[2] + red_s[3];
  float inv = 1.0f / s;

  ushort4* Pr = (ushort4*)(P + (size_t)row * 4096);
#pragma unroll
  for (int i = 0; i < 4; ++i) {
    ushort4 o;
    o.x = f2bf(e[i * 4 + 0] * inv);
    o.y = f2bf(e[i * 4 + 1] * inv);
    o.z = f2bf(e[i * 4 + 2] * inv);
    o.w = f2bf(e[i * 4 + 3] * inv);
    Pr[tid + i * 256] = o;
  }
}

// ---------------- launch ----------------
extern "C" void kernel_launch(void* const* d_in, const int* in_sizes, int n_in,
                              void* d_out, int out_size, void* d_ws, size_t ws_size,
                              hipStream_t stream) {
  const float* x  = (const float*)d_in[0];
  const float* Wq = (const float*)d_in[1];
  const float* Wk = (const float*)d_in[2];
  const float* Wv = (const float*)d_in[3];
  float* out = (float*)d_out;

  const size_t MT = (size_t)TB * TT;      // 16384 rows
  const size_t XE = MT * TD;              // 16,777,216
  const size_t WE = (size_t)TD * TD;      // 1,048,576

  u16* xb  = (u16*)d_ws;
  u16* wqb = xb + XE;
  u16* wkb = wqb + WE;
  u16* wvb = wkb + WE;
  u16* Q   = wvb + WE;
  u16* Kb  = Q + XE;
  u16* V   = Kb + XE;
  u16* Vt  = V + XE;
  float* S = (float*)(Vt + XE);           // TT*TT fp32 (one batch)
  u16* P   = xb;                          // reuse x_bf16 region (dead after QKV GEMMs)

  // casts
  cast_bf16<<<2048, 256, 0, stream>>>(x,  xb,  (int)(XE / 4));
  cast_bf16<<<512,  256, 0, stream>>>(Wq, wqb, (int)(WE / 4));
  cast_bf16<<<512,  256, 0, stream>>>(Wk, wkb, (int)(WE / 4));
  cast_bf16<<<512,  256, 0, stream>>>(Wv, wvb, (int)(WE / 4));

  // QKV projections: [16384,1024] x [1024,1024]^T, fold 1/sqrt(D)=1/32 into Q
  dim3 blk(256);
  dim3 gq(TD / 128, (unsigned)(MT / 128));
  gemm_bt<true><<<gq, blk, 0, stream>>>(xb, wqb, Q,  (int)MT, TD, TD, 0.03125f);
  gemm_bt<true><<<gq, blk, 0, stream>>>(xb, wkb, Kb, (int)MT, TD, TD, 1.0f);
  gemm_bt<true><<<gq, blk, 0, stream>>>(xb, wvb, V,  (int)MT, TD, TD, 1.0f);

  // V -> Vt
  transpose_bf16<<<dim3(TD / 32, TT / 32, TB), 256, 0, stream>>>(V, Vt);

  // per-batch attention
  for (int b = 0; b < TB; ++b) {
    const size_t ob = (size_t)b * TT * TD;
    gemm_bt<false><<<dim3(TT / 128, TT / 128), blk, 0, stream>>>(
        Q + ob, Kb + ob, S, TT, TT, TD, 1.0f);
    softmax_rows<<<TT, 256, 0, stream>>>(S, P);
    gemm_bt<false><<<dim3(TD / 128, TT / 128), blk, 0, stream>>>(
        P, Vt + ob, out + ob, TT, TD, TT, 1.0f);
  }
}

// Round 2
// 845.865 us; speedup vs baseline: 1.0981x; 1.0981x over previous
//
#include <hip/hip_runtime.h>
#include <stdint.h>

typedef unsigned short u16;
typedef __attribute__((ext_vector_type(4))) float f32x4;
typedef __attribute__((ext_vector_type(8))) short s16x8;

#define TB 4
#define TT 4096
#define TD 1024

__device__ __forceinline__ u16 f2bf(float f) {
  union { float f; uint32_t u; } v; v.f = f;
  return (u16)((v.u + 0x7FFFu + ((v.u >> 16) & 1u)) >> 16);
}

#define GLOAD_LDS16(g, l) __builtin_amdgcn_global_load_lds( \
    (const __attribute__((address_space(1))) void*)(g),      \
    (__attribute__((address_space(3))) void*)(l), 16, 0, 0)

// ---------------- cast fp32 -> bf16, vectorized ----------------
__global__ void cast_bf16(const float* __restrict__ in, u16* __restrict__ out, int n4) {
  int i = blockIdx.x * blockDim.x + threadIdx.x;
  int stride = gridDim.x * blockDim.x;
  for (; i < n4; i += stride) {
    float4 v = ((const float4*)in)[i];
    ushort4 o;
    o.x = f2bf(v.x); o.y = f2bf(v.y); o.z = f2bf(v.z); o.w = f2bf(v.w);
    ((ushort4*)out)[i] = o;
  }
}

// ---------------- GEMM: C[M,N] = A[M,K] * Bt[N,K]^T (both bf16, K contiguous) ----------------
// 128x128 tile, 256 threads (4 waves 2x2), BK=32, mfma_f32_16x16x32_bf16.
// LDS tiles XOR-swizzled: 16B chunk index ^= ((row>>1)&3); applied on the
// pre-swizzled GLOBAL source (global_load_lds writes linearly) and on the
// ds_read chunk index (same involution both sides).
// Per-z (blockIdx.z) element offsets sA/sB/sC allow batching and split-K.
template<bool OUT_BF16>
__global__ __launch_bounds__(256)
void gemm_bt(const u16* __restrict__ A, const u16* __restrict__ Bt,
             void* __restrict__ C, int M, int N, int K,
             int lda, int ldb, int ldc, float scale,
             size_t sA, size_t sB, size_t sC) {
  __shared__ u16 lsA[128 * 32];
  __shared__ u16 lsB[128 * 32];
  const int tid  = threadIdx.x;
  const int lane = tid & 63;
  const int wid  = tid >> 6;
  const int wm   = wid >> 1;   // 0..1
  const int wn   = wid & 1;    // 0..1
  const int brow = blockIdx.y * 128;
  const int bcol = blockIdx.x * 128;

  A  += (size_t)blockIdx.z * sA;
  Bt += (size_t)blockIdx.z * sB;

  f32x4 acc[4][4];
#pragma unroll
  for (int m = 0; m < 4; ++m)
#pragma unroll
    for (int n = 0; n < 4; ++n) acc[m][n] = (f32x4){0.f, 0.f, 0.f, 0.f};

  const int nk = K >> 5;  // BK = 32
  for (int kt = 0; kt < nk; ++kt) {
    // stage 128x32 bf16 tiles: 512 16B-chunks each, 2 per thread, pre-swizzled source
#pragma unroll
    for (int i = 0; i < 2; ++i) {
      int c    = i * 256 + tid;        // chunk id 0..511
      int row  = c >> 2;               // 0..127
      int col8 = (c & 3) ^ ((row >> 1) & 3);  // swizzled source chunk
      const u16* ga = A  + (size_t)(brow + row) * lda + kt * 32 + col8 * 8;
      const u16* gb = Bt + (size_t)(bcol + row) * ldb + kt * 32 + col8 * 8;
      // LDS dest is wave-uniform base; HW adds lane*16B (linear)
      u16* la = &lsA[(size_t)(i * 256 + wid * 64) * 8];
      u16* lb = &lsB[(size_t)(i * 256 + wid * 64) * 8];
      GLOAD_LDS16(ga, la);
      GLOAD_LDS16(gb, lb);
    }
    __syncthreads();

    const int r16 = lane & 15;
    const int k8  = lane >> 4;                 // 0..3
    const int ck  = k8 ^ ((r16 >> 1) & 3);     // swizzled read chunk
    s16x8 af[4], bf[4];
#pragma unroll
    for (int m = 0; m < 4; ++m)
      af[m] = *(const s16x8*)&lsA[(size_t)((wm * 64 + m * 16 + r16) * 4 + ck) * 8];
#pragma unroll
    for (int n = 0; n < 4; ++n)
      bf[n] = *(const s16x8*)&lsB[(size_t)((wn * 64 + n * 16 + r16) * 4 + ck) * 8];
#pragma unroll
    for (int m = 0; m < 4; ++m)
#pragma unroll
      for (int n = 0; n < 4; ++n)
        acc[m][n] = __builtin_amdgcn_mfma_f32_16x16x32_bf16(af[m], bf[n], acc[m][n], 0, 0, 0);
    __syncthreads();
  }

  // epilogue: C/D layout col = lane&15, row = (lane>>4)*4 + reg
  const int c16 = lane & 15;
  const int rhi = lane >> 4;
#pragma unroll
  for (int m = 0; m < 4; ++m)
#pragma unroll
    for (int n = 0; n < 4; ++n)
#pragma unroll
      for (int r = 0; r < 4; ++r) {
        int grow = brow + wm * 64 + m * 16 + rhi * 4 + r;
        int gcol = bcol + wn * 64 + n * 16 + c16;
        float v = acc[m][n][r] * scale;
        if (OUT_BF16) ((u16*)C)[(size_t)blockIdx.z * sC + (size_t)grow * ldc + gcol] = f2bf(v);
        else          ((float*)C)[(size_t)blockIdx.z * sC + (size_t)grow * ldc + gcol] = v;
      }
}

// ---------------- transpose bf16: V[B][T][D] -> Vt[B][D][T], 64x64 tiles ----------------
__global__ __launch_bounds__(256)
void transpose_bf16(const u16* __restrict__ V, u16* __restrict__ Vt) {
  __shared__ u16 tile[64][65];
  int b  = blockIdx.z;
  int t0 = blockIdx.y * 64;
  int e0 = blockIdx.x * 64;
  const u16* Vb  = V  + (size_t)b * TT * TD;
  u16*       Vtb = Vt + (size_t)b * TT * TD;
  int r  = threadIdx.x >> 4;   // 0..15
  int c4 = threadIdx.x & 15;   // 0..15 -> cols c4*4..+3
#pragma unroll
  for (int i = 0; i < 4; ++i) {
    int row = r + i * 16;
    ushort4 v = *(const ushort4*)&Vb[(size_t)(t0 + row) * TD + e0 + c4 * 4];
    tile[row][c4 * 4 + 0] = v.x;
    tile[row][c4 * 4 + 1] = v.y;
    tile[row][c4 * 4 + 2] = v.z;
    tile[row][c4 * 4 + 3] = v.w;
  }
  __syncthreads();
#pragma unroll
  for (int i = 0; i < 4; ++i) {
    int e = r + i * 16;
    ushort4 o;
    o.x = tile[c4 * 4 + 0][e];
    o.y = tile[c4 * 4 + 1][e];
    o.z = tile[c4 * 4 + 2][e];
    o.w = tile[c4 * 4 + 3][e];
    *(ushort4*)&Vtb[(size_t)(e0 + e) * TT + t0 + c4 * 4] = o;
  }
}

// ---------------- row softmax: S[4096] fp32 -> P[4096] bf16 (1/l folded in) ----------------
__global__ __launch_bounds__(256)
void softmax_rows(const float* __restrict__ S, u16* __restrict__ P) {
  __shared__ float red_m[4];
  __shared__ float red_s[4];
  int row  = blockIdx.x;
  int tid  = threadIdx.x;
  int lane = tid & 63;
  int wid  = tid >> 6;
  const float4* Sr = (const float4*)(S + (size_t)row * 4096);

  float4 v[4];
  float m = -1e30f;
#pragma unroll
  for (int i = 0; i < 4; ++i) {
    v[i] = Sr[tid + i * 256];
    m = fmaxf(m, fmaxf(fmaxf(v[i].x, v[i].y), fmaxf(v[i].z, v[i].w)));
  }
#pragma unroll
  for (int off = 32; off >= 1; off >>= 1) m = fmaxf(m, __shfl_xor(m, off));
  if (lane == 0) red_m[wid] = m;
  __syncthreads();
  m = fmaxf(fmaxf(red_m[0], red_m[1]), fmaxf(red_m[2], red_m[3]));

  float e[16];
  float s = 0.f;
#pragma unroll
  for (int i = 0; i < 4; ++i) {
    e[i * 4 + 0] = __expf(v[i].x - m);
    e[i * 4 + 1] = __expf(v[i].y - m);
    e[i * 4 + 2] = __expf(v[i].z - m);
    e[i * 4 + 3] = __expf(v[i].w - m);
    s += e[i * 4 + 0] + e[i * 4 + 1] + e[i * 4 + 2] + e[i * 4 + 3];
  }
#pragma unroll
  for (int off = 32; off >= 1; off >>= 1) s += __shfl_xor(s, off);
  if (lane == 0) red_s[wid] = s;
  __syncthreads();
  s = red_s[0] + red_s[1] + red_s[2] + red_s[3];
  float inv = 1.0f / s;

  ushort4* Pr = (ushort4*)(P + (size_t)row * 4096);
#pragma unroll
  for (int i = 0; i < 4; ++i) {
    ushort4 o;
    o.x = f2bf(e[i * 4 + 0] * inv);
    o.y = f2bf(e[i * 4 + 1] * inv);
    o.z = f2bf(e[i * 4 + 2] * inv);
    o.w = f2bf(e[i * 4 + 3] * inv);
    Pr[tid + i * 256] = o;
  }
}

// ---------------- split-K reduction: out = sum of 4 partials ----------------
__global__ void reduce4(const float* __restrict__ p, float* __restrict__ out, int n4) {
  const size_t s = (size_t)TT * TD / 4;
  int i = blockIdx.x * blockDim.x + threadIdx.x;
  int stride = gridDim.x * blockDim.x;
  for (; i < n4; i += stride) {
    float4 a = ((const float4*)p)[i];
    float4 b = ((const float4*)p)[i + s];
    float4 c = ((const float4*)p)[i + 2 * s];
    float4 d = ((const float4*)p)[i + 3 * s];
    float4 o;
    o.x = a.x + b.x + c.x + d.x;
    o.y = a.y + b.y + c.y + d.y;
    o.z = a.z + b.z + c.z + d.z;
    o.w = a.w + b.w + c.w + d.w;
    ((float4*)out)[i] = o;
  }
}

// ---------------- launch ----------------
extern "C" void kernel_launch(void* const* d_in, const int* in_sizes, int n_in,
                              void* d_out, int out_size, void* d_ws, size_t ws_size,
                              hipStream_t stream) {
  const float* x  = (const float*)d_in[0];
  const float* Wq = (const float*)d_in[1];
  const float* Wk = (const float*)d_in[2];
  const float* Wv = (const float*)d_in[3];
  float* out = (float*)d_out;

  const size_t MT = (size_t)TB * TT;      // 16384 rows
  const size_t BE = (size_t)TT * TD;      // per-batch Q/K/V elements (4,194,304)
  const size_t XE = MT * TD;              // 16,777,216
  const size_t PE = (size_t)TT * TT;      // per-batch score elements (16,777,216)
  const size_t WE = (size_t)TD * TD;      // 1,048,576

  u16* xb    = (u16*)d_ws;
  u16* wqb   = xb + XE;
  u16* wkb   = wqb + WE;
  u16* wvb   = wkb + WE;
  u16* Q     = wvb + WE;
  u16* Kb    = Q + XE;
  u16* Vt    = Kb + XE;
  u16* Sbase = Vt + XE;                   // 2*PE u16 = PE fp32 region
  float* S   = (float*)Sbase;
  u16* V     = Sbase;                     // V overlays S (dead after transpose)
  u16* P_all = Sbase + 2 * PE;            // big path only: B*PE u16

  const size_t need_big = ((size_t)(xb - xb) + XE + 3 * WE + 3 * XE + 2 * PE + (size_t)TB * PE) * 2;
  const bool big = ws_size >= need_big;

  // casts
  cast_bf16<<<2048, 256, 0, stream>>>(x,  xb,  (int)(XE / 4));
  cast_bf16<<<512,  256, 0, stream>>>(Wq, wqb, (int)(WE / 4));
  cast_bf16<<<512,  256, 0, stream>>>(Wk, wkb, (int)(WE / 4));
  cast_bf16<<<512,  256, 0, stream>>>(Wv, wvb, (int)(WE / 4));

  // QKV projections: [16384,1024] x [1024,1024]^T, fold 1/sqrt(D)=1/32 into Q
  dim3 blk(256);
  dim3 gq(TD / 128, (unsigned)(MT / 128), 1);
  gemm_bt<true><<<gq, blk, 0, stream>>>(xb, wqb, Q, (int)MT, TD, TD, TD, TD, TD, 0.03125f, 0, 0, 0);
  gemm_bt<true><<<gq, blk, 0, stream>>>(xb, wkb, Kb, (int)MT, TD, TD, TD, TD, TD, 1.0f, 0, 0, 0);
  gemm_bt<true><<<gq, blk, 0, stream>>>(xb, wvb, V, (int)MT, TD, TD, TD, TD, TD, 1.0f, 0, 0, 0);

  // V -> Vt (V lives in the S region; S is first written after this completes)
  transpose_bf16<<<dim3(TD / 64, TT / 64, TB), 256, 0, stream>>>(V, Vt);

  if (big) {
    // per-batch scores+softmax into P_all, then one batched PV (1024 blocks)
    for (int b = 0; b < TB; ++b) {
      gemm_bt<false><<<dim3(TT / 128, TT / 128, 1), blk, 0, stream>>>(
          Q + b * BE, Kb + b * BE, S, TT, TT, TD, TD, TD, TT, 1.0f, 0, 0, 0);
      softmax_rows<<<TT, 256, 0, stream>>>(S, P_all + b * PE);
    }
    gemm_bt<false><<<dim3(TD / 128, TT / 128, TB), blk, 0, stream>>>(
        P_all, Vt, out, TT, TD, TT, TT, TT, TD, 1.0f, PE, BE, BE);
  } else {
    // fallback: per-batch, P reuses xb, split-K PV into S region + reduce
    u16* P = xb;
    float* part = S;
    for (int b = 0; b < TB; ++b) {
      gemm_bt<false><<<dim3(TT / 128, TT / 128, 1), blk, 0, stream>>>(
          Q + b * BE, Kb + b * BE, S, TT, TT, TD, TD, TD, TT, 1.0f, 0, 0, 0);
      softmax_rows<<<TT, 256, 0, stream>>>(S, P);
      gemm_bt<false><<<dim3(TD / 128, TT / 128, 4), blk, 0, stream>>>(
          P, Vt + b * BE, part, TT, TD, TT / 4, TT, TT, TD, 1.0f,
          (size_t)(TT / 4), (size_t)(TT / 4), BE);
      reduce4<<<2048, 256, 0, stream>>>(part, out + b * BE, (int)(BE / 4));
    }
  }
}

// Round 3
// 569.082 us; speedup vs baseline: 1.6322x; 1.4864x over previous
//
#include <hip/hip_runtime.h>
#include <stdint.h>

typedef unsigned short u16;
typedef __attribute__((ext_vector_type(4))) float f32x4;
typedef __attribute__((ext_vector_type(8))) short s16x8;

#define TB 4
#define TT 4096
#define TD 1024

__device__ __forceinline__ u16 f2bf(float f) {
  union { float f; uint32_t u; } v; v.f = f;
  return (u16)((v.u + 0x7FFFu + ((v.u >> 16) & 1u)) >> 16);
}

#define GLOAD_LDS16(g, l) __builtin_amdgcn_global_load_lds( \
    (const __attribute__((address_space(1))) void*)(g),      \
    (__attribute__((address_space(3))) void*)(l), 16, 0, 0)

// ---------------- cast fp32 -> bf16, vectorized ----------------
__global__ void cast_bf16(const float* __restrict__ in, u16* __restrict__ out, int n4) {
  int i = blockIdx.x * blockDim.x + threadIdx.x;
  int stride = gridDim.x * blockDim.x;
  for (; i < n4; i += stride) {
    float4 v = ((const float4*)in)[i];
    ushort4 o;
    o.x = f2bf(v.x); o.y = f2bf(v.y); o.z = f2bf(v.z); o.w = f2bf(v.w);
    ((ushort4*)out)[i] = o;
  }
}

// ---------------- GEMM 256x256 tile, 8 waves (2Mx4N), BK=64 ----------------
// C[M,N] = A[M,K] * Bt[N,K]^T, bf16 in, fp32 acc. Counted-vmcnt pipeline:
// 2 LDS slots (tile double-buffer), 2-tile-deep global prefetch, raw barriers,
// vmcnt(8) steady-state (never 0 until the tail). LDS swizzle: 16B-chunk index
// ^= (row&7)  (conflict-free ds_read_b128), applied identically on the
// pre-swizzled global source (global_load_lds writes linearly) and the reads.
template<bool OUT_BF16>
__global__ __launch_bounds__(512)
void gemm256(const u16* __restrict__ A, const u16* __restrict__ Bt,
             void* __restrict__ C, int K,
             int lda, int ldb, int ldc, float scale,
             size_t sA, size_t sB, size_t sC) {
  // [slot(2)][op(2: A,B)][half(2)][row 128][chunk 8][8 u16] = 128 KiB
  __shared__ u16 ls[65536];
  const int tid  = threadIdx.x;
  const int lane = tid & 63;
  const int wid  = tid >> 6;   // 0..7
  const int wm   = wid >> 2;   // 0..1
  const int wn   = wid & 3;    // 0..3

  // bijective XCD-contiguous remap within the z-slice (nxy % 8 == 0 always here)
  const int nxy = gridDim.x * gridDim.y;
  const int id  = blockIdx.y * gridDim.x + blockIdx.x;
  const int sid = (id & 7) * (nxy >> 3) + (id >> 3);
  const int bx  = sid % gridDim.x;
  const int by  = sid / gridDim.x;
  const int brow = by * 256;
  const int bcol = bx * 256;

  A  += (size_t)blockIdx.z * sA;
  Bt += (size_t)blockIdx.z * sB;

  // staging: per thread 8 x gload_lds per K-tile.
  // dest chunk (linear) = i*512 + wid*64 + lane  -> row r = i*64+wid*8+(lane>>3),
  // physical chunk p = lane&7; content must be logical chunk p^(r&7) = (lane&7)^(lane>>3).
  const int lr = lane >> 3;           // = r & 7
  const int lc = (lane & 7) ^ lr;     // swizzled logical chunk to fetch

  f32x4 acc[8][4];
#pragma unroll
  for (int m = 0; m < 8; ++m)
#pragma unroll
    for (int n = 0; n < 4; ++n) acc[m][n] = (f32x4){0.f, 0.f, 0.f, 0.f};

  const int nt = K >> 6;  // BK = 64

  auto STAGE = [&](int slot, int kt) {
    const int sb = slot * 32768;
#pragma unroll
    for (int i = 0; i < 2; ++i) {
      const int r  = i * 64 + wid * 8 + lr;           // row within half (0..127)
      const int db = sb + (i * 512 + wid * 64) * 8;   // wave-uniform dest base (u16 idx)
      const size_t col = (size_t)kt * 64 + lc * 8;
      GLOAD_LDS16(A  + (size_t)(brow +       r) * lda + col, &ls[db]);
      GLOAD_LDS16(A  + (size_t)(brow + 128 + r) * lda + col, &ls[db + 8192]);
      GLOAD_LDS16(Bt + (size_t)(bcol +       r) * ldb + col, &ls[db + 16384]);
      GLOAD_LDS16(Bt + (size_t)(bcol + 128 + r) * ldb + col, &ls[db + 24576]);
    }
  };

  STAGE(0, 0);
  if (nt > 1) STAGE(1, 1);

  // fragment read bases (u16 index, without slot / kk-chunk)
  const int r16 = lane & 15;
  const int k8  = lane >> 4;   // 0..3
  const int sw  = r16 & 7;
  const int c0  = (((0 << 2) | k8) ^ sw) * 8;   // kk=0 chunk byte-swizzled
  const int c1  = (((1 << 2) | k8) ^ sw) * 8;   // kk=1
  int aBase[8], bBase[4];
#pragma unroll
  for (int m = 0; m < 8; ++m) aBase[m] = wm * 8192 + (m * 16 + r16) * 64;
#pragma unroll
  for (int n = 0; n < 4; ++n) {
    int row = wn * 64 + n * 16 + r16;
    bBase[n] = 16384 + (row >> 7) * 8192 + (row & 127) * 64;
  }

  for (int t = 0; t < nt; ++t) {
    const int sb = (t & 1) * 32768;
    // tile t must be resident: 2-deep prefetch -> wait all but the newest 8
    if (t + 1 < nt) asm volatile("s_waitcnt vmcnt(8)" ::: "memory");
    else            asm volatile("s_waitcnt vmcnt(0)" ::: "memory");
    __builtin_amdgcn_s_barrier();
    __builtin_amdgcn_sched_barrier(0);

    s16x8 a0[8], b0[4];
#pragma unroll
    for (int m = 0; m < 8; ++m) a0[m] = *(const s16x8*)&ls[sb + aBase[m] + c0];
#pragma unroll
    for (int n = 0; n < 4; ++n) b0[n] = *(const s16x8*)&ls[sb + bBase[n] + c0];

    __builtin_amdgcn_s_setprio(1);
#pragma unroll
    for (int m = 0; m < 8; ++m)
#pragma unroll
      for (int n = 0; n < 4; ++n)
        acc[m][n] = __builtin_amdgcn_mfma_f32_16x16x32_bf16(a0[m], b0[n], acc[m][n], 0, 0, 0);
    __builtin_amdgcn_s_setprio(0);

    s16x8 a1[8], b1[4];
#pragma unroll
    for (int m = 0; m < 8; ++m) a1[m] = *(const s16x8*)&ls[sb + aBase[m] + c1];
#pragma unroll
    for (int n = 0; n < 4; ++n) b1[n] = *(const s16x8*)&ls[sb + bBase[n] + c1];

    // all of this wave's reads of slot (t&1) must complete before any wave
    // overwrites it with tile t+2
    asm volatile("s_waitcnt lgkmcnt(0)" ::: "memory");
    __builtin_amdgcn_s_barrier();
    __builtin_amdgcn_sched_barrier(0);
    if (t + 2 < nt) STAGE(t & 1, t + 2);

    __builtin_amdgcn_s_setprio(1);
#pragma unroll
    for (int m = 0; m < 8; ++m)
#pragma unroll
      for (int n = 0; n < 4; ++n)
        acc[m][n] = __builtin_amdgcn_mfma_f32_16x16x32_bf16(a1[m], b1[n], acc[m][n], 0, 0, 0);
    __builtin_amdgcn_s_setprio(0);
  }

  // epilogue: C/D layout col = lane&15, row = (lane>>4)*4 + reg
  const int c16 = lane & 15;
  const int rhi = lane >> 4;
#pragma unroll
  for (int m = 0; m < 8; ++m)
#pragma unroll
    for (int n = 0; n < 4; ++n)
#pragma unroll
      for (int r = 0; r < 4; ++r) {
        int grow = brow + wm * 128 + m * 16 + rhi * 4 + r;
        int gcol = bcol + wn * 64 + n * 16 + c16;
        float v = acc[m][n][r] * scale;
        if (OUT_BF16) ((u16*)C)[(size_t)blockIdx.z * sC + (size_t)grow * ldc + gcol] = f2bf(v);
        else          ((float*)C)[(size_t)blockIdx.z * sC + (size_t)grow * ldc + gcol] = v;
      }
}

// ---------------- transpose bf16: V[B][T][D] -> Vt[B][D][T], 64x64 tiles ----------------
__global__ __launch_bounds__(256)
void transpose_bf16(const u16* __restrict__ V, u16* __restrict__ Vt) {
  __shared__ u16 tile[64][65];
  int b  = blockIdx.z;
  int t0 = blockIdx.y * 64;
  int e0 = blockIdx.x * 64;
  const u16* Vb  = V  + (size_t)b * TT * TD;
  u16*       Vtb = Vt + (size_t)b * TT * TD;
  int r  = threadIdx.x >> 4;   // 0..15
  int c4 = threadIdx.x & 15;   // 0..15 -> cols c4*4..+3
#pragma unroll
  for (int i = 0; i < 4; ++i) {
    int row = r + i * 16;
    ushort4 v = *(const ushort4*)&Vb[(size_t)(t0 + row) * TD + e0 + c4 * 4];
    tile[row][c4 * 4 + 0] = v.x;
    tile[row][c4 * 4 + 1] = v.y;
    tile[row][c4 * 4 + 2] = v.z;
    tile[row][c4 * 4 + 3] = v.w;
  }
  __syncthreads();
#pragma unroll
  for (int i = 0; i < 4; ++i) {
    int e = r + i * 16;
    ushort4 o;
    o.x = tile[c4 * 4 + 0][e];
    o.y = tile[c4 * 4 + 1][e];
    o.z = tile[c4 * 4 + 2][e];
    o.w = tile[c4 * 4 + 3][e];
    *(ushort4*)&Vtb[(size_t)(e0 + e) * TT + t0 + c4 * 4] = o;
  }
}

// ---------------- row softmax: S[4096] fp32 -> P[4096] bf16 (1/l folded in) ----------------
__global__ __launch_bounds__(256)
void softmax_rows(const float* __restrict__ S, u16* __restrict__ P) {
  __shared__ float red_m[4];
  __shared__ float red_s[4];
  int row  = blockIdx.x;
  int tid  = threadIdx.x;
  int lane = tid & 63;
  int wid  = tid >> 6;
  const float4* Sr = (const float4*)(S + (size_t)row * 4096);

  float4 v[4];
  float m = -1e30f;
#pragma unroll
  for (int i = 0; i < 4; ++i) {
    v[i] = Sr[tid + i * 256];
    m = fmaxf(m, fmaxf(fmaxf(v[i].x, v[i].y), fmaxf(v[i].z, v[i].w)));
  }
#pragma unroll
  for (int off = 32; off >= 1; off >>= 1) m = fmaxf(m, __shfl_xor(m, off));
  if (lane == 0) red_m[wid] = m;
  __syncthreads();
  m = fmaxf(fmaxf(red_m[0], red_m[1]), fmaxf(red_m[2], red_m[3]));

  float e[16];
  float s = 0.f;
#pragma unroll
  for (int i = 0; i < 4; ++i) {
    e[i * 4 + 0] = __expf(v[i].x - m);
    e[i * 4 + 1] = __expf(v[i].y - m);
    e[i * 4 + 2] = __expf(v[i].z - m);
    e[i * 4 + 3] = __expf(v[i].w - m);
    s += e[i * 4 + 0] + e[i * 4 + 1] + e[i * 4 + 2] + e[i * 4 + 3];
  }
#pragma unroll
  for (int off = 32; off >= 1; off >>= 1) s += __shfl_xor(s, off);
  if (lane == 0) red_s[wid] = s;
  __syncthreads();
  s = red_s[0] + red_s[1] + red_s[2] + red_s[3];
  float inv = 1.0f / s;

  ushort4* Pr = (ushort4*)(P + (size_t)row * 4096);
#pragma unroll
  for (int i = 0; i < 4; ++i) {
    ushort4 o;
    o.x = f2bf(e[i * 4 + 0] * inv);
    o.y = f2bf(e[i * 4 + 1] * inv);
    o.z = f2bf(e[i * 4 + 2] * inv);
    o.w = f2bf(e[i * 4 + 3] * inv);
    Pr[tid + i * 256] = o;
  }
}

// ---------------- split-K reduction: out = sum of 4 partials ----------------
__global__ void reduce4(const float* __restrict__ p, float* __restrict__ out, int n4) {
  const size_t s = (size_t)TT * TD / 4;
  int i = blockIdx.x * blockDim.x + threadIdx.x;
  int stride = gridDim.x * blockDim.x;
  for (; i < n4; i += stride) {
    float4 a = ((const float4*)p)[i];
    float4 b = ((const float4*)p)[i + s];
    float4 c = ((const float4*)p)[i + 2 * s];
    float4 d = ((const float4*)p)[i + 3 * s];
    float4 o;
    o.x = a.x + b.x + c.x + d.x;
    o.y = a.y + b.y + c.y + d.y;
    o.z = a.z + b.z + c.z + d.z;
    o.w = a.w + b.w + c.w + d.w;
    ((float4*)out)[i] = o;
  }
}

// ---------------- launch ----------------
extern "C" void kernel_launch(void* const* d_in, const int* in_sizes, int n_in,
                              void* d_out, int out_size, void* d_ws, size_t ws_size,
                              hipStream_t stream) {
  const float* x  = (const float*)d_in[0];
  const float* Wq = (const float*)d_in[1];
  const float* Wk = (const float*)d_in[2];
  const float* Wv = (const float*)d_in[3];
  float* out = (float*)d_out;

  const size_t MT = (size_t)TB * TT;      // 16384 rows
  const size_t BE = (size_t)TT * TD;      // per-batch Q/K/V elements
  const size_t XE = MT * TD;              // 16,777,216
  const size_t PE = (size_t)TT * TT;      // per-batch score elements
  const size_t WE = (size_t)TD * TD;      // 1,048,576

  u16* xb    = (u16*)d_ws;
  u16* wqb   = xb + XE;
  u16* wkb   = wqb + WE;
  u16* wvb   = wkb + WE;
  u16* Q     = wvb + WE;
  u16* Kb    = Q + XE;
  u16* Vt    = Kb + XE;
  u16* Sbase = Vt + XE;                   // 2*PE u16 = PE fp32 region
  float* S   = (float*)Sbase;
  u16* V     = Sbase;                     // V overlays S (dead after transpose)
  u16* P_all = Sbase + 2 * PE;            // big path only: B*PE u16

  const size_t need_big = (XE + 3 * WE + 3 * XE + 2 * PE + (size_t)TB * PE) * 2;
  const bool big = ws_size >= need_big;

  // casts
  cast_bf16<<<2048, 256, 0, stream>>>(x,  xb,  (int)(XE / 4));
  cast_bf16<<<512,  256, 0, stream>>>(Wq, wqb, (int)(WE / 4));
  cast_bf16<<<512,  256, 0, stream>>>(Wk, wkb, (int)(WE / 4));
  cast_bf16<<<512,  256, 0, stream>>>(Wv, wvb, (int)(WE / 4));

  // QKV projections: [16384,1024] x [1024,1024]^T, fold 1/sqrt(D)=1/32 into Q
  dim3 blk(512);
  dim3 gq(TD / 256, (unsigned)(MT / 256), 1);
  gemm256<true><<<gq, blk, 0, stream>>>(xb, wqb, Q,  TD, TD, TD, TD, 0.03125f, 0, 0, 0);
  gemm256<true><<<gq, blk, 0, stream>>>(xb, wkb, Kb, TD, TD, TD, TD, 1.0f, 0, 0, 0);
  gemm256<true><<<gq, blk, 0, stream>>>(xb, wvb, V,  TD, TD, TD, TD, 1.0f, 0, 0, 0);

  // V -> Vt (V lives in the S region; S is first written after this completes)
  transpose_bf16<<<dim3(TD / 64, TT / 64, TB), 256, 0, stream>>>(V, Vt);

  if (big) {
    for (int b = 0; b < TB; ++b) {
      gemm256<false><<<dim3(TT / 256, TT / 256, 1), blk, 0, stream>>>(
          Q + b * BE, Kb + b * BE, S, TD, TD, TD, TT, 1.0f, 0, 0, 0);
      softmax_rows<<<TT, 256, 0, stream>>>(S, P_all + b * PE);
    }
    gemm256<false><<<dim3(TD / 256, TT / 256, TB), blk, 0, stream>>>(
        P_all, Vt, out, TT, TT, TT, TD, 1.0f, PE, BE, BE);
  } else {
    // fallback: per-batch, P reuses xb, split-K PV into S region + reduce
    u16* P = xb;
    float* part = S;
    for (int b = 0; b < TB; ++b) {
      gemm256<false><<<dim3(TT / 256, TT / 256, 1), blk, 0, stream>>>(
          Q + b * BE, Kb + b * BE, S, TD, TD, TD, TT, 1.0f, 0, 0, 0);
      softmax_rows<<<TT, 256, 0, stream>>>(S, P);
      gemm256<false><<<dim3(TD / 256, TT / 256, 4), blk, 0, stream>>>(
          P, Vt + b * BE, part, TT / 4, TT, TT, TD, 1.0f,
          (size_t)(TT / 4), (size_t)(TT / 4), BE);
      reduce4<<<2048, 256, 0, stream>>>(part, out + b * BE, (int)(BE / 4));
    }
  }
}